// Round 1
// baseline (169.993 us; speedup 1.0000x reference)
//
#include <hip/hip_runtime.h>

#define BSZ 64
#define SEQ 512
#define HD  768
#define TT  64   // topic/token list length
#define SL  8    // slices (blocks) per batch
#define WPB 4    // waves per block (256 threads)

__global__ __launch_bounds__(256) void fused_bilinear_kernel(
    const float* __restrict__ hidden,     // [64,512,768]
    const float* __restrict__ Wsrc,       // [862,384]
    const float* __restrict__ Wtgt,       // [862,384]
    const float* __restrict__ W_cls,      // [2,6144]
    const float* __restrict__ b_cls,      // [2]
    const float* __restrict__ W_topic,    // [2,6144]
    const float* __restrict__ b_topic,    // [2]
    const float* __restrict__ W_token,    // [2,6144]
    const float* __restrict__ b_token,    // [2]
    const int*   __restrict__ source_ids, // [64]
    const int*   __restrict__ target_ids, // [64]
    const int*   __restrict__ topic_inds, // [64,64]
    const float* __restrict__ topic_mask, // [64,64]
    const int*   __restrict__ token_inds, // [64,64]
    const float* __restrict__ token_mask, // [64,64]
    float*       __restrict__ out)        // [128 + 8192 + 8192]
{
    __shared__ __align__(16) float dom[HD];        // domain vector d0 for this batch
    __shared__ __align__(16) float V[3 * 2 * HD];  // effective weights [w][o][d]

    const int b     = blockIdx.x / SL;
    const int slice = blockIdx.x % SL;
    const int tid   = threadIdx.x;

    // ---- stage domain = concat(Wsrc[src], Wtgt[tgt]) ----
    const int sid = source_ids[b];
    const int tgt = target_ids[b];
    for (int j = tid; j < HD; j += 256) {
        dom[j] = (j < 384) ? Wsrc[sid * 384 + j] : Wtgt[tgt * 384 + (j - 384)];
    }
    __syncthreads();

    // ---- effective weights: V[w][o][m*8+c] = sum_a dom[m*8+a] * W[o, m*64+a*8+c] ----
    const float* Ws[3] = {W_cls, W_topic, W_token};
    for (int w = 0; w < 3; ++w) {
        const float* Wp = Ws[w];
        for (int o = 0; o < 2; ++o) {
            for (int d = tid; d < HD; d += 256) {
                const int m = d >> 3, c = d & 7;
                const float* wrow = Wp + o * 6144 + m * 64 + c;
                float acc = 0.f;
                #pragma unroll
                for (int a = 0; a < 8; ++a)
                    acc = fmaf(dom[m * 8 + a], wrow[a * 8], acc);
                V[(w * 2 + o) * HD + d] = acc;
            }
        }
    }
    __syncthreads();

    const int wave = tid >> 6;
    const int lane = tid & 63;

    // tasks per batch: t=0 -> cls; t in [1,64] -> topic l=t-1; t in [65,128] -> token l=t-65
    for (int t = slice * WPB + wave; t < 129; t += SL * WPB) {
        int w, pos, outoff;
        float mask;
        const float* bias;
        bool do_softmax;
        if (t == 0) {
            w = 0; pos = 0; mask = 1.f; bias = b_cls; do_softmax = true;
            outoff = b * 2;
        } else if (t <= 64) {
            const int l = t - 1;
            w = 1; pos = topic_inds[b * TT + l]; mask = topic_mask[b * TT + l];
            bias = b_topic; do_softmax = true;
            outoff = 128 + (b * TT + l) * 2;
        } else {
            const int l = t - 65;
            w = 2; pos = token_inds[b * TT + l]; mask = token_mask[b * TT + l];
            bias = b_token; do_softmax = false;
            outoff = 128 + BSZ * TT * 2 + (b * TT + l) * 2;
        }

        const float4* hrow = reinterpret_cast<const float4*>(
            hidden + ((size_t)b * SEQ + (size_t)pos) * HD);
        const float4* v0 = reinterpret_cast<const float4*>(&V[(w * 2 + 0) * HD]);
        const float4* v1 = reinterpret_cast<const float4*>(&V[(w * 2 + 1) * HD]);

        float a0 = 0.f, a1 = 0.f;
        #pragma unroll
        for (int k = 0; k < 3; ++k) {          // 768 floats = 192 float4 = 64 lanes x 3
            const float4 h4 = hrow[lane + k * 64];
            const float4 x0 = v0[lane + k * 64];
            const float4 x1 = v1[lane + k * 64];
            a0 = fmaf(h4.x, x0.x, a0); a0 = fmaf(h4.y, x0.y, a0);
            a0 = fmaf(h4.z, x0.z, a0); a0 = fmaf(h4.w, x0.w, a0);
            a1 = fmaf(h4.x, x1.x, a1); a1 = fmaf(h4.y, x1.y, a1);
            a1 = fmaf(h4.z, x1.z, a1); a1 = fmaf(h4.w, x1.w, a1);
        }
        #pragma unroll
        for (int off = 32; off > 0; off >>= 1) {
            a0 += __shfl_down(a0, off, 64);
            a1 += __shfl_down(a1, off, 64);
        }

        if (lane == 0) {
            const float l0 = fmaf(mask, a0, bias[0]);
            const float l1 = fmaf(mask, a1, bias[1]);
            if (do_softmax) {
                const float mx = fmaxf(l0, l1);
                const float e0 = __expf(l0 - mx);
                const float e1 = __expf(l1 - mx);
                const float inv = 1.f / (e0 + e1);
                out[outoff]     = e0 * inv;
                out[outoff + 1] = e1 * inv;
            } else {
                out[outoff]     = l0;
                out[outoff + 1] = l1;
            }
        }
    }
}

extern "C" void kernel_launch(void* const* d_in, const int* in_sizes, int n_in,
                              void* d_out, int out_size, void* d_ws, size_t ws_size,
                              hipStream_t stream) {
    const float* hidden     = (const float*)d_in[0];
    const float* Wsrc       = (const float*)d_in[1];
    const float* Wtgt       = (const float*)d_in[2];
    const float* W_cls      = (const float*)d_in[3];
    const float* b_cls      = (const float*)d_in[4];
    const float* W_topic    = (const float*)d_in[5];
    const float* b_topic    = (const float*)d_in[6];
    const float* W_token    = (const float*)d_in[7];
    const float* b_token    = (const float*)d_in[8];
    const int*   source_ids = (const int*)d_in[9];
    const int*   target_ids = (const int*)d_in[10];
    // d_in[11] ent_inds, d_in[12] ent_mask: dead code in reference (never used in outputs)
    const int*   topic_inds = (const int*)d_in[13];
    const float* topic_mask = (const float*)d_in[14];
    const int*   token_inds = (const int*)d_in[15];
    const float* token_mask = (const float*)d_in[16];
    float* out = (float*)d_out;

    fused_bilinear_kernel<<<BSZ * SL, 256, 0, stream>>>(
        hidden, Wsrc, Wtgt, W_cls, b_cls, W_topic, b_topic, W_token, b_token,
        source_ids, target_ids, topic_inds, topic_mask, token_inds, token_mask, out);
}

// Round 2
// 165.685 us; speedup vs baseline: 1.0260x; 1.0260x over previous
//
#include <hip/hip_runtime.h>

#define BSZ 64
#define SEQ 512
#define HD  768
#define TT  64    // topic/token list length
#define NROW 6    // 3 weight sets x 2 outputs
#define NTASK 129 // 1 cls + 64 topic + 64 token per batch

// ---------------------------------------------------------------------------
// Kernel 1: per-batch effective weights
//   V[b][w*2+o][m*8+c] = sum_a dom[b][m*8+a] * W_w[o][m*64+a*8+c]
// 64 blocks (one per batch) x 256 threads. Output: d_ws, [64][6][768] floats.
// ---------------------------------------------------------------------------
__global__ __launch_bounds__(256) void compute_V_kernel(
    const float* __restrict__ Wsrc,       // [862,384]
    const float* __restrict__ Wtgt,       // [862,384]
    const float* __restrict__ W_cls,      // [2,6144]
    const float* __restrict__ W_topic,    // [2,6144]
    const float* __restrict__ W_token,    // [2,6144]
    const int*   __restrict__ source_ids, // [64]
    const int*   __restrict__ target_ids, // [64]
    float*       __restrict__ Vg)         // [64,6,768]
{
    __shared__ __align__(16) float dom[HD];
    const int b   = blockIdx.x;
    const int tid = threadIdx.x;

    const int sid = source_ids[b];
    const int tgt = target_ids[b];
    for (int j = tid; j < HD; j += 256)
        dom[j] = (j < 384) ? Wsrc[sid * 384 + j] : Wtgt[tgt * 384 + (j - 384)];
    __syncthreads();

    for (int idx = tid; idx < NROW * HD; idx += 256) {
        const int r = idx / HD;          // 0..5 = w*2+o
        const int d = idx - r * HD;
        const int w = r >> 1, o = r & 1;
        const float* Wp = (w == 0) ? W_cls : (w == 1) ? W_topic : W_token;
        const int m = d >> 3, c = d & 7;
        const float* wrow = Wp + o * 6144 + m * 64 + c;
        float acc = 0.f;
        #pragma unroll
        for (int a = 0; a < 8; ++a)
            acc = fmaf(dom[m * 8 + a], wrow[a * 8], acc);
        Vg[(size_t)b * (NROW * HD) + idx] = acc;
    }
}

// ---------------------------------------------------------------------------
// Kernel 2: one wave per task. 8256 tasks = 64 batches x 129.
// grid = 2064 blocks x 256 threads (4 waves/block).
// ---------------------------------------------------------------------------
__global__ __launch_bounds__(256) void task_kernel(
    const float* __restrict__ hidden,     // [64,512,768]
    const float* __restrict__ Vg,         // [64,6,768]
    const float* __restrict__ b_cls,      // [2]
    const float* __restrict__ b_topic,    // [2]
    const float* __restrict__ b_token,    // [2]
    const int*   __restrict__ topic_inds, // [64,64]
    const float* __restrict__ topic_mask, // [64,64]
    const int*   __restrict__ token_inds, // [64,64]
    const float* __restrict__ token_mask, // [64,64]
    float*       __restrict__ out)        // [128 + 8192 + 8192]
{
    const int wg   = blockIdx.x * 4 + (threadIdx.x >> 6);
    const int lane = threadIdx.x & 63;
    const int b    = wg / NTASK;
    const int t    = wg - b * NTASK;

    int w, pos, outoff;
    float mask;
    const float* bias;
    bool do_softmax;
    if (t == 0) {
        w = 0; pos = 0; mask = 1.f; bias = b_cls; do_softmax = true;
        outoff = b * 2;
    } else if (t <= TT) {
        const int l = t - 1;
        w = 1; pos = topic_inds[b * TT + l]; mask = topic_mask[b * TT + l];
        bias = b_topic; do_softmax = true;
        outoff = 128 + (b * TT + l) * 2;
    } else {
        const int l = t - 1 - TT;
        w = 2; pos = token_inds[b * TT + l]; mask = token_mask[b * TT + l];
        bias = b_token; do_softmax = false;
        outoff = 128 + BSZ * TT * 2 + (b * TT + l) * 2;
    }

    const float4* hrow = reinterpret_cast<const float4*>(
        hidden + ((size_t)b * SEQ + (size_t)pos) * HD);
    const float4* v0 = reinterpret_cast<const float4*>(
        Vg + ((size_t)b * NROW + w * 2 + 0) * HD);
    const float4* v1 = reinterpret_cast<const float4*>(
        Vg + ((size_t)b * NROW + w * 2 + 1) * HD);

    float a0 = 0.f, a1 = 0.f;
    #pragma unroll
    for (int k = 0; k < 3; ++k) {          // 768 floats = 192 float4 = 64 lanes x 3
        const float4 h4 = hrow[lane + k * 64];
        const float4 x0 = v0[lane + k * 64];
        const float4 x1 = v1[lane + k * 64];
        a0 = fmaf(h4.x, x0.x, a0); a1 = fmaf(h4.x, x1.x, a1);
        a0 = fmaf(h4.y, x0.y, a0); a1 = fmaf(h4.y, x1.y, a1);
        a0 = fmaf(h4.z, x0.z, a0); a1 = fmaf(h4.z, x1.z, a1);
        a0 = fmaf(h4.w, x0.w, a0); a1 = fmaf(h4.w, x1.w, a1);
    }
    #pragma unroll
    for (int off = 32; off > 0; off >>= 1) {
        a0 += __shfl_down(a0, off, 64);
        a1 += __shfl_down(a1, off, 64);
    }

    if (lane == 0) {
        const float l0 = fmaf(mask, a0, bias[0]);
        const float l1 = fmaf(mask, a1, bias[1]);
        if (do_softmax) {
            const float mx = fmaxf(l0, l1);
            const float e0 = __expf(l0 - mx);
            const float e1 = __expf(l1 - mx);
            const float inv = 1.f / (e0 + e1);
            out[outoff]     = e0 * inv;
            out[outoff + 1] = e1 * inv;
        } else {
            out[outoff]     = l0;
            out[outoff + 1] = l1;
        }
    }
}

extern "C" void kernel_launch(void* const* d_in, const int* in_sizes, int n_in,
                              void* d_out, int out_size, void* d_ws, size_t ws_size,
                              hipStream_t stream) {
    const float* hidden     = (const float*)d_in[0];
    const float* Wsrc       = (const float*)d_in[1];
    const float* Wtgt       = (const float*)d_in[2];
    const float* W_cls      = (const float*)d_in[3];
    const float* b_cls      = (const float*)d_in[4];
    const float* W_topic    = (const float*)d_in[5];
    const float* b_topic    = (const float*)d_in[6];
    const float* W_token    = (const float*)d_in[7];
    const float* b_token    = (const float*)d_in[8];
    const int*   source_ids = (const int*)d_in[9];
    const int*   target_ids = (const int*)d_in[10];
    // d_in[11] ent_inds, d_in[12] ent_mask: dead in reference (never used)
    const int*   topic_inds = (const int*)d_in[13];
    const float* topic_mask = (const float*)d_in[14];
    const int*   token_inds = (const int*)d_in[15];
    const float* token_mask = (const float*)d_in[16];
    float* out = (float*)d_out;
    float* Vg  = (float*)d_ws;   // [64,6,768] = 1.18 MB

    compute_V_kernel<<<BSZ, 256, 0, stream>>>(
        Wsrc, Wtgt, W_cls, W_topic, W_token, source_ids, target_ids, Vg);

    // 64 batches * 129 tasks = 8256 waves, 4 waves/block -> 2064 blocks
    task_kernel<<<(BSZ * NTASK) / 4, 256, 0, stream>>>(
        hidden, Vg, b_cls, b_topic, b_token,
        topic_inds, topic_mask, token_inds, token_mask, out);
}